// Round 4
// baseline (2955.052 us; speedup 1.0000x reference)
//
#include <hip/hip_runtime.h>

#define NN 4096
#define NSTEPS 100
#define TPB 512
#define NBLK 256     // 1 block per CU; 16 rows per block, K pinned in VGPRs
#define CSTRIDE 16   // chunk counters padded to 64B

// Coherent (cross-XCD) 8-byte ops: relaxed agent-scope atomics → sc-flagged
// global ops that bypass non-coherent L1/L2, with NO wbl2/inv cache ops.
__device__ __forceinline__ void zstore(float2* p, float2 v) {
    union { float2 f; unsigned long long u; } c; c.f = v;
    __hip_atomic_store((unsigned long long*)p, c.u, __ATOMIC_RELAXED,
                       __HIP_MEMORY_SCOPE_AGENT);
}
__device__ __forceinline__ float2 zload(const float2* p) {
    unsigned long long u = __hip_atomic_load((const unsigned long long*)p,
                                             __ATOMIC_RELAXED,
                                             __HIP_MEMORY_SCOPE_AGENT);
    union { unsigned long long u; float2 f; } c; c.u = u;
    return c.f;
}

// Persistent dataflow kernel. Chunk c = z[256c, 256c+256), produced by blocks
// [16c, 16c+16). chunkcnt[c] is a monotonic counter: 16*(s+1) when chunk c of
// step s+1's input (i.e. z_{s+1}) is fully visible at the coherence point.
// Within a block: wave w stages chunks {2w, 2w+1} into LDS (parity-buffered)
// and publishes an LDS generation flag; dot-waves consume chunks as ready.
__global__ __launch_bounds__(TPB, 2) void k_persist(
    const float* __restrict__ K, const float2* __restrict__ z0,
    float2* __restrict__ zb0, float2* __restrict__ zb1,
    float2* __restrict__ zfinal, const float* __restrict__ omega_p,
    const float* __restrict__ dt_p, int* chunkcnt) {
    __shared__ float zr[2][NN];          // parity-double-buffered z (SoA)
    __shared__ float zi[2][NN];
    __shared__ float P[2][8][8];         // per-wave partials, parity-buffered
    __shared__ int lds_ready[16];        // per-chunk staged generation

    const int tid  = threadIdx.x;
    const int bid  = blockIdx.x;
    const int w    = tid >> 6, lane = tid & 63;
    const int g    = w >> 1,   h    = w & 1;
    const int rb   = bid * 16 + g * 4;           // wave's first row
    const int mychunk = 2 * w + (lane >> 5);     // staging chunk (32 thr each)
    const int q    = lane & 31;
    const int sbase = 256 * mychunk + 8 * q;     // staging z base index

    const float omega = *omega_p;
    const float dt    = *dt_p;
    const float inv2n = 1.0f / (2.0f * NN);

    // ---- K fragment: 4 rows x 8 float4 = 128 VGPRs ----
    float4 kA[4][8];
#pragma unroll
    for (int r = 0; r < 4; ++r) {
        const float* Kr = K + (size_t)(rb + r) * NN + h * 2048 + lane * 4;
#pragma unroll
        for (int j = 0; j < 8; ++j) kA[r][j] = *(const float4*)(Kr + j * 256);
    }

    if (tid < 16) lds_ready[tid] = 0;
    __syncthreads();

    for (int s = 0; s < NSTEPS; ++s) {
        const int par = s & 1;
        // Pin kA in registers (opaque redefinition: no refold/spill).
#pragma unroll
        for (int r = 0; r < 4; ++r)
#pragma unroll
            for (int j = 0; j < 8; ++j)
                asm volatile("" : "+v"(kA[r][j].x), "+v"(kA[r][j].y),
                                  "+v"(kA[r][j].z), "+v"(kA[r][j].w));

        // ---- stage my chunk: 32 threads x 8 z values ----
        float2 v[8];
        if (s == 0) {
            const float2* src = z0 + sbase;      // pristine input, plain loads
#pragma unroll
            for (int i = 0; i < 8; ++i) v[i] = src[i];
        } else {
            const float2* zsrc = par ? zb1 : zb0;     // z_s lives in zbuf[s&1]
            const int need = 16 * s;
            const int* cp = chunkcnt + mychunk * CSTRIDE;
            for (;;) {
                int c = __hip_atomic_load(cp, __ATOMIC_RELAXED,
                                          __HIP_MEMORY_SCOPE_AGENT);
                if (__all(c >= need)) break;
                __builtin_amdgcn_s_sleep(1);
            }
            __atomic_signal_fence(__ATOMIC_SEQ_CST);
#pragma unroll
            for (int i = 0; i < 8; ++i) v[i] = zload(zsrc + sbase + i);
        }
#pragma unroll
        for (int i = 0; i < 8; ++i) {
            zr[par][sbase + i] = v[i].x;
            zi[par][sbase + i] = v[i].y;
        }
        __threadfence_block();                   // drain ds writes (lgkmcnt)
        if (q == 0) *(volatile int*)&lds_ready[mychunk] = s + 1;

        // ---- dots: consume chunks as they become ready ----
        float sr0 = 0, sr1 = 0, sr2 = 0, sr3 = 0;
        float si0 = 0, si1 = 0, si2 = 0, si3 = 0;
        const int jrot = bid & 7;                // spread chunk demand
#pragma unroll
        for (int jj = 0; jj < 8; ++jj) {
            const int j = (jj + jrot) & 7;
            const int c = h * 8 + j;
            while (*(volatile int*)&lds_ready[c] < s + 1) {}
            __atomic_signal_fence(__ATOMIC_SEQ_CST);
            const float4 a = *(const float4*)&zr[par][c * 256 + lane * 4];
            const float4 b = *(const float4*)&zi[par][c * 256 + lane * 4];
            const float4 k0 = kA[0][j], k1 = kA[1][j];
            const float4 k2 = kA[2][j], k3 = kA[3][j];
            sr0 += k0.x * a.x + k0.y * a.y + k0.z * a.z + k0.w * a.w;
            si0 += k0.x * b.x + k0.y * b.y + k0.z * b.z + k0.w * b.w;
            sr1 += k1.x * a.x + k1.y * a.y + k1.z * a.z + k1.w * a.w;
            si1 += k1.x * b.x + k1.y * b.y + k1.z * b.z + k1.w * b.w;
            sr2 += k2.x * a.x + k2.y * a.y + k2.z * a.z + k2.w * a.w;
            si2 += k2.x * b.x + k2.y * b.y + k2.z * b.z + k2.w * b.w;
            sr3 += k3.x * a.x + k3.y * a.y + k3.z * a.z + k3.w * a.w;
            si3 += k3.x * b.x + k3.y * b.y + k3.z * b.z + k3.w * b.w;
        }
#pragma unroll
        for (int off = 32; off; off >>= 1) {
            sr0 += __shfl_xor(sr0, off, 64); si0 += __shfl_xor(si0, off, 64);
            sr1 += __shfl_xor(sr1, off, 64); si1 += __shfl_xor(si1, off, 64);
            sr2 += __shfl_xor(sr2, off, 64); si2 += __shfl_xor(si2, off, 64);
            sr3 += __shfl_xor(sr3, off, 64); si3 += __shfl_xor(si3, off, 64);
        }
        if (lane == 0) {
            P[par][w][0] = sr0; P[par][w][1] = sr1;
            P[par][w][2] = sr2; P[par][w][3] = sr3;
            P[par][w][4] = si0; P[par][w][5] = si1;
            P[par][w][6] = si2; P[par][w][7] = si3;
        }
        __syncthreads();

        // ---- per-row ODE update (wave 0, threads 0..15) + publish ----
        float2* zo = (s == NSTEPS - 1) ? zfinal : (((s + 1) & 1) ? zb1 : zb0);
        if (tid < 16) {
            const int g2 = tid >> 2, i = tid & 3;
            float u = P[par][2 * g2][i]     + P[par][2 * g2 + 1][i];
            float vv = P[par][2 * g2][4 + i] + P[par][2 * g2 + 1][4 + i];
            const int gr = bid * 16 + tid;
            float x = zr[par][gr], y = zi[par][gr];
            float A = x * x - y * y;             // Re(z^2)
            float B = 2.0f * x * y;              // Im(z^2)
            float dzr = inv2n * (u - (u * A + vv * B)) + omega * x;
            float dzi = inv2n * (vv - (u * B - vv * A)) + omega * y;
            float nx = x + dt * dzr;
            float ny = y + dt * dzi;
            float a2 = nx * nx + ny * ny;
            if (a2 >= 0.999f * 0.999f) {
                float sc = 0.999f / sqrtf(a2);
                nx *= sc; ny *= sc;
            }
            if (s == NSTEPS - 1) zo[gr] = make_float2(nx, ny);
            else                 zstore(zo + gr, make_float2(nx, ny));
        }
        if (s != NSTEPS - 1 && w == 0) {
            __builtin_amdgcn_s_waitcnt(0);       // z stores ack'd at coh point
            __atomic_signal_fence(__ATOMIC_SEQ_CST);
            if (tid == 0)
                __hip_atomic_fetch_add(&chunkcnt[(bid >> 4) * CSTRIDE], 1,
                                       __ATOMIC_RELAXED, __HIP_MEMORY_SCOPE_AGENT);
        }
    }
}

// ---- generic fallback: per-step launches ----
__global__ __launch_bounds__(256) void k_step_f32(
    const float* __restrict__ K, const float2* __restrict__ zin,
    float2* __restrict__ zout, const float* __restrict__ omega_p,
    const float* __restrict__ dt_p, int n) {
    const int wave = threadIdx.x >> 6;
    const int lane = threadIdx.x & 63;
    const int row  = blockIdx.x * 4 + wave;
    if (row >= n) return;
    float sr = 0.0f, si = 0.0f;
    for (int c = lane; c < n; c += 64) {
        float k = K[(size_t)row * n + c];
        float2 z = zin[c];
        sr += k * z.x;
        si += k * z.y;
    }
#pragma unroll
    for (int off = 32; off; off >>= 1) {
        sr += __shfl_down(sr, off, 64);
        si += __shfl_down(si, off, 64);
    }
    if (lane == 0) {
        float u = sr, v = si;
        float2 zc = zin[row];
        float x = zc.x, y = zc.y;
        float inv2n = 1.0f / (2.0f * n);
        float A = x * x - y * y, B = 2.0f * x * y;
        float dzr = inv2n * (u - (u * A + v * B)) + (*omega_p) * x;
        float dzi = inv2n * (v - (u * B - v * A)) + (*omega_p) * y;
        float nx = x + (*dt_p) * dzr, ny = y + (*dt_p) * dzi;
        float a2 = nx * nx + ny * ny;
        if (a2 >= 0.999f * 0.999f) { float sc = 0.999f / sqrtf(a2); nx *= sc; ny *= sc; }
        zout[row] = make_float2(nx, ny);
    }
}

extern "C" void kernel_launch(void* const* d_in, const int* in_sizes, int n_in,
                              void* d_out, int out_size, void* d_ws, size_t ws_size,
                              hipStream_t stream) {
    const float2* z0      = (const float2*)d_in[0];
    const float*  K       = (const float*)d_in[1];
    const float*  omega_p = (const float*)d_in[2];
    const float*  dt_p    = (const float*)d_in[3];
    const int n = in_sizes[0] / 2;
    float2* out = (float2*)d_out;

    const size_t cnt_bytes = 16 * CSTRIDE * sizeof(int);  // 1 KB
    const size_t need = cnt_bytes + 2 * (size_t)NN * sizeof(float2);
    if (n == NN && ws_size >= need) {
        int*    chunkcnt = (int*)d_ws;
        float2* zb0 = (float2*)((char*)d_ws + cnt_bytes);
        float2* zb1 = zb0 + NN;
        hipMemsetAsync(d_ws, 0, cnt_bytes, stream);
        k_persist<<<NBLK, TPB, 0, stream>>>(K, z0, zb0, zb1, out,
                                            omega_p, dt_p, chunkcnt);
    } else {
        float2* zb0 = (float2*)d_ws;
        float2* zb1 = zb0 + n;
        const float2* cur = z0;
        for (int s = 0; s < NSTEPS; ++s) {
            float2* nxt = (s == NSTEPS - 1) ? out : ((s & 1) ? zb1 : zb0);
            k_step_f32<<<(n + 3) / 4, 256, 0, stream>>>(K, cur, nxt, omega_p, dt_p, n);
            cur = nxt;
        }
    }
}

// Round 5
// 736.768 us; speedup vs baseline: 4.0108x; 4.0108x over previous
//
#include <hip/hip_runtime.h>

#define NN 4096
#define NSTEPS 100
#define TPB 512
#define NBLK 256     // 1 block per CU; 16 rows per block, K pinned in VGPRs
#define CSTRIDE 16   // 64B padding for counters / gen words

// Coherent (cross-XCD) 8-byte load/store: relaxed agent-scope atomics compile
// to sc-flagged global ops that bypass the non-coherent L1/L2 and hit the
// coherence point directly — WITHOUT the buffer_wbl2 / buffer_inv cache
// maintenance that release/acquire fences emit (the R1 killer).
__device__ __forceinline__ void zstore(float2* p, float2 v) {
    union { float2 f; unsigned long long u; } c; c.f = v;
    __hip_atomic_store((unsigned long long*)p, c.u, __ATOMIC_RELAXED,
                       __HIP_MEMORY_SCOPE_AGENT);
}
__device__ __forceinline__ float2 zload(const float2* p) {
    unsigned long long u = __hip_atomic_load((const unsigned long long*)p,
                                             __ATOMIC_RELAXED,
                                             __HIP_MEMORY_SCOPE_AGENT);
    union { unsigned long long u; float2 f; } c; c.u = u;
    return c.f;
}

// Persistent kernel: K in VGPRs (asm-pinned), z staged to LDS each step.
// Barrier v3: arrival via 16 padded atomic counters (1 add per block);
// block 0 wave 0 alone polls them; fan-out via 32 padded gen words each
// polled by ONE lane of 8 blocks; intra-block broadcast via LDS.
__global__ __launch_bounds__(TPB, 2) void k_persist(
    const float* __restrict__ K, const float2* __restrict__ z0,
    float2* __restrict__ zb0, float2* __restrict__ zb1,
    float2* __restrict__ zfinal, const float* __restrict__ omega_p,
    const float* __restrict__ dt_p, int* flags) {
    __shared__ float zr[NN];
    __shared__ float zi[NN];
    __shared__ float P[8][8];
    __shared__ int lbar;

    const int tid  = threadIdx.x;
    const int bid  = blockIdx.x;
    const int w    = tid >> 6, lane = tid & 63;
    const int g    = w >> 1,   h    = w & 1;
    const int rb   = bid * 16 + g * 4;          // first of this wave's 4 rows
    const int cb   = h * 2048 + lane * 4;       // lane's col base (j stride 256)

    int* agg = flags;                 // 16 arrival counters (64B apart)
    int* gen = flags + 16 * CSTRIDE;  // 32 generation words (64B apart)

    const float omega = *omega_p;
    const float dt    = *dt_p;
    const float inv2n = 1.0f / (2.0f * NN);

    if (tid == 0) lbar = 0;

    // ---- load K fragment: 4 rows x 8 float4 = 128 VGPRs ----
    float4 kA[4][8];
#pragma unroll
    for (int r = 0; r < 4; ++r) {
        const float* Kr = K + (size_t)(rb + r) * NN + cb;
#pragma unroll
        for (int j = 0; j < 8; ++j) kA[r][j] = *(const float4*)(Kr + j * 256);
    }

    const float2* zin = z0;
    for (int s = 0; s < NSTEPS; ++s) {
        // Pin kA in registers: opaque redefinition each iteration so the
        // compiler can neither spill-and-reload nor refold the global loads.
#pragma unroll
        for (int r = 0; r < 4; ++r)
#pragma unroll
            for (int j = 0; j < 8; ++j)
                asm volatile("" : "+v"(kA[r][j].x), "+v"(kA[r][j].y),
                                  "+v"(kA[r][j].z), "+v"(kA[r][j].w));

        // ---- stage z -> LDS (SoA), coherent loads, conflict-free ----
#pragma unroll
        for (int it = 0; it < 8; ++it) {
            int idx = it * TPB + tid;            // 0..4095
            float2 v = zload(zin + idx);
            zr[idx] = v.x; zi[idx] = v.y;
        }
        __syncthreads();

        // ---- dots: 4 rows x 2048 cols per wave, K from regs, z from LDS ----
        float sr0 = 0, sr1 = 0, sr2 = 0, sr3 = 0;
        float si0 = 0, si1 = 0, si2 = 0, si3 = 0;
#pragma unroll
        for (int j = 0; j < 8; ++j) {
            float4 a = *(const float4*)&zr[cb + j * 256];
            float4 b = *(const float4*)&zi[cb + j * 256];
            float4 k0 = kA[0][j], k1 = kA[1][j], k2 = kA[2][j], k3 = kA[3][j];
            sr0 += k0.x * a.x + k0.y * a.y + k0.z * a.z + k0.w * a.w;
            si0 += k0.x * b.x + k0.y * b.y + k0.z * b.z + k0.w * b.w;
            sr1 += k1.x * a.x + k1.y * a.y + k1.z * a.z + k1.w * a.w;
            si1 += k1.x * b.x + k1.y * b.y + k1.z * b.z + k1.w * b.w;
            sr2 += k2.x * a.x + k2.y * a.y + k2.z * a.z + k2.w * a.w;
            si2 += k2.x * b.x + k2.y * b.y + k2.z * b.z + k2.w * b.w;
            sr3 += k3.x * a.x + k3.y * a.y + k3.z * a.z + k3.w * a.w;
            si3 += k3.x * b.x + k3.y * b.y + k3.z * b.z + k3.w * b.w;
        }
#pragma unroll
        for (int off = 32; off; off >>= 1) {
            sr0 += __shfl_xor(sr0, off, 64); si0 += __shfl_xor(si0, off, 64);
            sr1 += __shfl_xor(sr1, off, 64); si1 += __shfl_xor(si1, off, 64);
            sr2 += __shfl_xor(sr2, off, 64); si2 += __shfl_xor(si2, off, 64);
            sr3 += __shfl_xor(sr3, off, 64); si3 += __shfl_xor(si3, off, 64);
        }
        if (lane == 0) {
            P[w][0] = sr0; P[w][1] = sr1; P[w][2] = sr2; P[w][3] = sr3;
            P[w][4] = si0; P[w][5] = si1; P[w][6] = si2; P[w][7] = si3;
        }
        __syncthreads();

        // ---- per-row ODE update (wave 0, threads 0..15) ----
        float2* zo = (s == NSTEPS - 1) ? zfinal : ((s & 1) ? zb1 : zb0);
        if (tid < 16) {
            int g2 = tid >> 2, i = tid & 3;
            float u = P[2 * g2][i]     + P[2 * g2 + 1][i];      // Re(K z)
            float v = P[2 * g2][4 + i] + P[2 * g2 + 1][4 + i];  // Im(K z)
            int gr = bid * 16 + tid;
            float x = zr[gr], y = zi[gr];
            float A = x * x - y * y;           // Re(z^2)
            float B = 2.0f * x * y;            // Im(z^2)
            float dzr = inv2n * (u - (u * A + v * B)) + omega * x;
            float dzi = inv2n * (v - (u * B - v * A)) + omega * y;
            float nx = x + dt * dzr;
            float ny = y + dt * dzi;
            float a2 = nx * nx + ny * ny;
            if (a2 >= 0.999f * 0.999f) {
                float sc = 0.999f / sqrtf(a2);
                nx *= sc; ny *= sc;
            }
            zstore(zo + gr, make_float2(nx, ny));
        }

        // ---- barrier v3 (skip after last step) ----
        if (s != NSTEPS - 1) {
            const int target = s + 1;
            if (w == 0) {
                __builtin_amdgcn_s_waitcnt(0);   // z stores ack'd at coh point
                __atomic_signal_fence(__ATOMIC_SEQ_CST);
                if (lane == 0)
                    __hip_atomic_fetch_add(&agg[(bid >> 4) * CSTRIDE], 1,
                                           __ATOMIC_RELAXED,
                                           __HIP_MEMORY_SCOPE_AGENT);
                if (bid == 0) {
                    const int need = 16 * target;
                    for (;;) {
                        int c = (lane < 16)
                            ? __hip_atomic_load(&agg[lane * CSTRIDE],
                                                __ATOMIC_RELAXED,
                                                __HIP_MEMORY_SCOPE_AGENT)
                            : need;
                        if (__all(c >= need)) break;
                        __builtin_amdgcn_s_sleep(1);
                    }
                    __atomic_signal_fence(__ATOMIC_SEQ_CST);
                    if (lane < 32)
                        __hip_atomic_store(&gen[lane * CSTRIDE], target,
                                           __ATOMIC_RELAXED,
                                           __HIP_MEMORY_SCOPE_AGENT);
                } else {
                    if (lane == 0) {
                        while (__hip_atomic_load(&gen[(bid >> 3) * CSTRIDE],
                                                 __ATOMIC_RELAXED,
                                                 __HIP_MEMORY_SCOPE_AGENT) < target)
                            __builtin_amdgcn_s_sleep(1);
                    }
                }
                __atomic_signal_fence(__ATOMIC_SEQ_CST);
                if (lane == 0) *(volatile int*)&lbar = target;
            } else {
                while (*(volatile int*)&lbar < target) __builtin_amdgcn_s_sleep(1);
                __atomic_signal_fence(__ATOMIC_SEQ_CST);
            }
        }
        zin = zo;
    }
}

// ---- generic fallback: per-step launches ----
__global__ __launch_bounds__(256) void k_step_f32(
    const float* __restrict__ K, const float2* __restrict__ zin,
    float2* __restrict__ zout, const float* __restrict__ omega_p,
    const float* __restrict__ dt_p, int n) {
    const int wave = threadIdx.x >> 6;
    const int lane = threadIdx.x & 63;
    const int row  = blockIdx.x * 4 + wave;
    if (row >= n) return;
    float sr = 0.0f, si = 0.0f;
    for (int c = lane; c < n; c += 64) {
        float k = K[(size_t)row * n + c];
        float2 z = zin[c];
        sr += k * z.x;
        si += k * z.y;
    }
#pragma unroll
    for (int off = 32; off; off >>= 1) {
        sr += __shfl_down(sr, off, 64);
        si += __shfl_down(si, off, 64);
    }
    if (lane == 0) {
        float u = sr, v = si;
        float2 zc = zin[row];
        float x = zc.x, y = zc.y;
        float inv2n = 1.0f / (2.0f * n);
        float A = x * x - y * y, B = 2.0f * x * y;
        float dzr = inv2n * (u - (u * A + v * B)) + (*omega_p) * x;
        float dzi = inv2n * (v - (u * B - v * A)) + (*omega_p) * y;
        float nx = x + (*dt_p) * dzr, ny = y + (*dt_p) * dzi;
        float a2 = nx * nx + ny * ny;
        if (a2 >= 0.999f * 0.999f) { float sc = 0.999f / sqrtf(a2); nx *= sc; ny *= sc; }
        zout[row] = make_float2(nx, ny);
    }
}

extern "C" void kernel_launch(void* const* d_in, const int* in_sizes, int n_in,
                              void* d_out, int out_size, void* d_ws, size_t ws_size,
                              hipStream_t stream) {
    const float2* z0      = (const float2*)d_in[0];
    const float*  K       = (const float*)d_in[1];
    const float*  omega_p = (const float*)d_in[2];
    const float*  dt_p    = (const float*)d_in[3];
    const int n = in_sizes[0] / 2;
    float2* out = (float2*)d_out;

    const size_t flags_bytes = 4096;  // 16 counters + 32 gen words, 64B-padded
    const size_t need = flags_bytes + 2 * (size_t)NN * sizeof(float2);
    if (n == NN && ws_size >= need) {
        int*    flags = (int*)d_ws;
        float2* zb0   = (float2*)((char*)d_ws + flags_bytes);
        float2* zb1   = zb0 + NN;
        hipMemsetAsync(d_ws, 0, flags_bytes, stream);
        k_persist<<<NBLK, TPB, 0, stream>>>(K, z0, zb0, zb1, out,
                                            omega_p, dt_p, flags);
    } else {
        float2* zb0 = (float2*)d_ws;
        float2* zb1 = zb0 + n;
        const float2* cur = z0;
        for (int s = 0; s < NSTEPS; ++s) {
            float2* nxt = (s == NSTEPS - 1) ? out : ((s & 1) ? zb1 : zb0);
            k_step_f32<<<(n + 3) / 4, 256, 0, stream>>>(K, cur, nxt, omega_p, dt_p, n);
            cur = nxt;
        }
    }
}

// Round 6
// 716.768 us; speedup vs baseline: 4.1227x; 1.0279x over previous
//
#include <hip/hip_runtime.h>

#define NN 4096
#define NSTEPS 100
#define TPB 512
#define NBLK 256     // 1 block per CU; 16 rows per block, K pinned in VGPRs

// Coherent (cross-XCD) 8-byte load/store: relaxed agent-scope atomics compile
// to sc-flagged global ops that bypass the non-coherent L1/L2 and hit the
// coherence point directly — WITHOUT the buffer_wbl2 / buffer_inv cache
// maintenance that release/acquire fences emit (the R1 killer).
__device__ __forceinline__ void zstore_u64(float2* p, unsigned long long u) {
    __hip_atomic_store((unsigned long long*)p, u, __ATOMIC_RELAXED,
                       __HIP_MEMORY_SCOPE_AGENT);
}
__device__ __forceinline__ unsigned long long zload_u64(const float2* p) {
    return __hip_atomic_load((const unsigned long long*)p, __ATOMIC_RELAXED,
                             __HIP_MEMORY_SCOPE_AGENT);
}

// Barrier-free persistent kernel. z_g (g>=1) lives in zb[g&1]; each element's
// x-mantissa low 3 bits carry tag = g&7. Stale content in zb[g&1] is z_{g-2}
// (tag differs by 2 mod 8) or memset-0 (tag 0, first writes have tag 1/2) —
// always distinguishable. Producers publish with ONE relaxed store (no fence,
// no waitcnt, no flag); consumers poll the data itself until tags match.
__global__ __launch_bounds__(TPB, 2) void k_persist(
    const float* __restrict__ K, const float2* __restrict__ z0,
    float2* __restrict__ zb0, float2* __restrict__ zb1,
    float2* __restrict__ zfinal, const float* __restrict__ omega_p,
    const float* __restrict__ dt_p) {
    __shared__ float zr[NN];
    __shared__ float zi[NN];
    __shared__ float P[8][8];

    const int tid  = threadIdx.x;
    const int bid  = blockIdx.x;
    const int w    = tid >> 6, lane = tid & 63;
    const int g    = w >> 1,   h    = w & 1;
    const int rb   = bid * 16 + g * 4;          // first of this wave's 4 rows
    const int cb   = h * 2048 + lane * 4;       // lane's col base (j stride 256)

    const float omega = *omega_p;
    const float dt    = *dt_p;
    const float inv2n = 1.0f / (2.0f * NN);

    // ---- load K fragment: 4 rows x 8 float4 = 128 VGPRs ----
    float4 kA[4][8];
#pragma unroll
    for (int r = 0; r < 4; ++r) {
        const float* Kr = K + (size_t)(rb + r) * NN + cb;
#pragma unroll
        for (int j = 0; j < 8; ++j) kA[r][j] = *(const float4*)(Kr + j * 256);
    }

    for (int s = 0; s < NSTEPS; ++s) {
        // Pin kA in registers: opaque redefinition each iteration so the
        // compiler can neither spill-and-reload nor refold the global loads.
#pragma unroll
        for (int r = 0; r < 4; ++r)
#pragma unroll
            for (int j = 0; j < 8; ++j)
                asm volatile("" : "+v"(kA[r][j].x), "+v"(kA[r][j].y),
                                  "+v"(kA[r][j].z), "+v"(kA[r][j].w));

        // ---- stage z_s -> LDS (SoA), conflict-free ----
        if (s == 0) {
#pragma unroll
            for (int it = 0; it < 8; ++it) {
                int idx = it * TPB + tid;
                float2 v = z0[idx];
                zr[idx] = v.x; zi[idx] = v.y;
            }
        } else {
            const float2* zsrc = (s & 1) ? zb1 : zb0;
            const unsigned tag = (unsigned)(s & 7);
            const int rot = bid & 7;             // spread chunk demand
            int idx[8];
            unsigned long long v[8];
#pragma unroll
            for (int it = 0; it < 8; ++it) {     // 8 loads in flight
                idx[it] = ((it + rot) & 7) * TPB + tid;
                v[it] = zload_u64(zsrc + idx[it]);
            }
#pragma unroll
            for (int it = 0; it < 8; ++it) {     // retry only stale elements
                while (((unsigned)v[it] & 7u) != tag) {
                    __builtin_amdgcn_s_sleep(1);
                    v[it] = zload_u64(zsrc + idx[it]);
                }
            }
#pragma unroll
            for (int it = 0; it < 8; ++it) {
                union { unsigned u; float f; } cx, cy;
                cx.u = (unsigned)v[it];
                cy.u = (unsigned)(v[it] >> 32);
                zr[idx[it]] = cx.f; zi[idx[it]] = cy.f;
            }
        }
        __syncthreads();

        // ---- dots: 4 rows x 2048 cols per wave, K from regs, z from LDS ----
        float sr0 = 0, sr1 = 0, sr2 = 0, sr3 = 0;
        float si0 = 0, si1 = 0, si2 = 0, si3 = 0;
#pragma unroll
        for (int j = 0; j < 8; ++j) {
            float4 a = *(const float4*)&zr[cb + j * 256];
            float4 b = *(const float4*)&zi[cb + j * 256];
            float4 k0 = kA[0][j], k1 = kA[1][j], k2 = kA[2][j], k3 = kA[3][j];
            sr0 += k0.x * a.x + k0.y * a.y + k0.z * a.z + k0.w * a.w;
            si0 += k0.x * b.x + k0.y * b.y + k0.z * b.z + k0.w * b.w;
            sr1 += k1.x * a.x + k1.y * a.y + k1.z * a.z + k1.w * a.w;
            si1 += k1.x * b.x + k1.y * b.y + k1.z * b.z + k1.w * b.w;
            sr2 += k2.x * a.x + k2.y * a.y + k2.z * a.z + k2.w * a.w;
            si2 += k2.x * b.x + k2.y * b.y + k2.z * b.z + k2.w * b.w;
            sr3 += k3.x * a.x + k3.y * a.y + k3.z * a.z + k3.w * a.w;
            si3 += k3.x * b.x + k3.y * b.y + k3.z * b.z + k3.w * b.w;
        }
#pragma unroll
        for (int off = 32; off; off >>= 1) {
            sr0 += __shfl_xor(sr0, off, 64); si0 += __shfl_xor(si0, off, 64);
            sr1 += __shfl_xor(sr1, off, 64); si1 += __shfl_xor(si1, off, 64);
            sr2 += __shfl_xor(sr2, off, 64); si2 += __shfl_xor(si2, off, 64);
            sr3 += __shfl_xor(sr3, off, 64); si3 += __shfl_xor(si3, off, 64);
        }
        if (lane == 0) {
            P[w][0] = sr0; P[w][1] = sr1; P[w][2] = sr2; P[w][3] = sr3;
            P[w][4] = si0; P[w][5] = si1; P[w][6] = si2; P[w][7] = si3;
        }
        __syncthreads();

        // ---- per-row ODE update (wave 0, threads 0..15) + publish ----
        if (tid < 16) {
            int g2 = tid >> 2, i = tid & 3;
            float u = P[2 * g2][i]     + P[2 * g2 + 1][i];      // Re(K z)
            float v = P[2 * g2][4 + i] + P[2 * g2 + 1][4 + i];  // Im(K z)
            int gr = bid * 16 + tid;
            float x = zr[gr], y = zi[gr];
            float A = x * x - y * y;           // Re(z^2)
            float B = 2.0f * x * y;            // Im(z^2)
            float dzr = inv2n * (u - (u * A + v * B)) + omega * x;
            float dzi = inv2n * (v - (u * B - v * A)) + omega * y;
            float nx = x + dt * dzr;
            float ny = y + dt * dzi;
            float a2 = nx * nx + ny * ny;
            if (a2 >= 0.999f * 0.999f) {
                float sc = 0.999f / sqrtf(a2);
                nx *= sc; ny *= sc;
            }
            if (s == NSTEPS - 1) {
                zfinal[gr] = make_float2(nx, ny);    // plain, untagged
            } else {
                union { float f; unsigned u; } cx, cy;
                cx.f = nx; cy.f = ny;
                cx.u = (cx.u & ~7u) | (unsigned)((s + 1) & 7);  // tag in x LSBs
                unsigned long long pk =
                    (unsigned long long)cx.u |
                    ((unsigned long long)cy.u << 32);
                float2* zo = ((s + 1) & 1) ? zb1 : zb0;
                zstore_u64(zo + gr, pk);             // fire-and-forget
            }
        }
        // no barrier — consumers self-gate on tags
    }
}

// ---- generic fallback: per-step launches ----
__global__ __launch_bounds__(256) void k_step_f32(
    const float* __restrict__ K, const float2* __restrict__ zin,
    float2* __restrict__ zout, const float* __restrict__ omega_p,
    const float* __restrict__ dt_p, int n) {
    const int wave = threadIdx.x >> 6;
    const int lane = threadIdx.x & 63;
    const int row  = blockIdx.x * 4 + wave;
    if (row >= n) return;
    float sr = 0.0f, si = 0.0f;
    for (int c = lane; c < n; c += 64) {
        float k = K[(size_t)row * n + c];
        float2 z = zin[c];
        sr += k * z.x;
        si += k * z.y;
    }
#pragma unroll
    for (int off = 32; off; off >>= 1) {
        sr += __shfl_down(sr, off, 64);
        si += __shfl_down(si, off, 64);
    }
    if (lane == 0) {
        float u = sr, v = si;
        float2 zc = zin[row];
        float x = zc.x, y = zc.y;
        float inv2n = 1.0f / (2.0f * n);
        float A = x * x - y * y, B = 2.0f * x * y;
        float dzr = inv2n * (u - (u * A + v * B)) + (*omega_p) * x;
        float dzi = inv2n * (v - (u * B - v * A)) + (*omega_p) * y;
        float nx = x + (*dt_p) * dzr, ny = y + (*dt_p) * dzi;
        float a2 = nx * nx + ny * ny;
        if (a2 >= 0.999f * 0.999f) { float sc = 0.999f / sqrtf(a2); nx *= sc; ny *= sc; }
        zout[row] = make_float2(nx, ny);
    }
}

extern "C" void kernel_launch(void* const* d_in, const int* in_sizes, int n_in,
                              void* d_out, int out_size, void* d_ws, size_t ws_size,
                              hipStream_t stream) {
    const float2* z0      = (const float2*)d_in[0];
    const float*  K       = (const float*)d_in[1];
    const float*  omega_p = (const float*)d_in[2];
    const float*  dt_p    = (const float*)d_in[3];
    const int n = in_sizes[0] / 2;
    float2* out = (float2*)d_out;

    const size_t need = 2 * (size_t)NN * sizeof(float2);   // two z buffers
    if (n == NN && ws_size >= need) {
        float2* zb0 = (float2*)d_ws;
        float2* zb1 = zb0 + NN;
        hipMemsetAsync(d_ws, 0, need, stream);   // tag 0 != any live tag (1,2)
        k_persist<<<NBLK, TPB, 0, stream>>>(K, z0, zb0, zb1, out,
                                            omega_p, dt_p);
    } else {
        float2* zb0 = (float2*)d_ws;
        float2* zb1 = zb0 + n;
        const float2* cur = z0;
        for (int s = 0; s < NSTEPS; ++s) {
            float2* nxt = (s == NSTEPS - 1) ? out : ((s & 1) ? zb1 : zb0);
            k_step_f32<<<(n + 3) / 4, 256, 0, stream>>>(K, cur, nxt, omega_p, dt_p, n);
            cur = nxt;
        }
    }
}